// Round 6
// baseline (130.574 us; speedup 1.0000x reference)
//
#include <hip/hip_runtime.h>
#include <stdint.h>

#define DM_ 256
#define H_ 4
#define M_ 4096
#define KN_ 16
#define B_ 2
#define MK_ (M_*KN_)

typedef __attribute__((ext_vector_type(8))) short short8;
typedef __attribute__((ext_vector_type(4))) float f32x4;
typedef __attribute__((ext_vector_type(4))) unsigned short u16x4;

static __device__ __forceinline__ unsigned short f2bf(float x) {
  union { float f; uint32_t u; } v; v.f = x;
  uint32_t u = v.u + (0x7FFFu + ((v.u >> 16) & 1u));  // RNE
  return (unsigned short)(u >> 16);
}
static __device__ __forceinline__ float u2f(uint32_t u) {
  union { uint32_t u; float f; } v; v.u = u; return v.f;
}

// XOR swizzle for [col][k] bf16 tiles (row stride 512 B), bank-floor b128 reads/writes.
static __device__ __forceinline__ int swz512(int col, int kbyte) {
  int f = ((col >> 2) & 7) ^ ((col & 1) << 2);
  return (col << 9) + (kbyte ^ (f << 4));
}

// ---- prep2: weight products, fragment-linear bf16, fused biases ------------------------
__global__ void prep2(const float* __restrict__ Wq, const float* __restrict__ bq,
                      const float* __restrict__ Wk, const float* __restrict__ Wv,
                      const float* __restrict__ bv, const float* __restrict__ Wm,
                      const float* __restrict__ bm,
                      unsigned short* __restrict__ W2T, unsigned short* __restrict__ Wmv,
                      float* __restrict__ qb2, float* __restrict__ btot) {
  int t = blockIdx.x * 512 + threadIdx.x;
  if (t < 262144) {                       // W2T fragment-linear [kstep8][rowblk64][lane][8]
    int j = t & 7, lane = (t >> 3) & 63, rowblk = (t >> 9) & 63, kstep = t >> 15;
    int row = rowblk * 16 + (lane & 15);
    int k = kstep * 32 + (lane >> 4) * 8 + j;
    int h = row >> 8, c = row & 255;
    float v = 0.f;
#pragma unroll 8
    for (int d = 0; d < 64; ++d) v += Wq[(4 * d + h) * 256 + k] * Wk[(4 * d + h) * 256 + c];
    W2T[t] = f2bf(v);
  } else if (t < 524288) {                // Wmv fragment-linear [kstep32][rowblk16][lane][8]
    int e = t - 262144;
    int j = e & 7, lane = (e >> 3) & 63, rowblk = (e >> 9) & 15, kstep = e >> 13;
    int o = rowblk * 16 + (lane & 15);
    int kidx = kstep * 32 + (lane >> 4) * 8 + j;
    int c = kidx >> 2, h = kidx & 3;
    float v = 0.f;
#pragma unroll 8
    for (int d = 0; d < 64; ++d) v += Wm[o * 256 + 4 * d + h] * Wv[(4 * d + h) * 256 + c];
    Wmv[e] = f2bf(v);
  } else if (t < 525312) {
    int r = t - 524288; int h = r >> 8, c = r & 255;
    float v = 0.f;
#pragma unroll 8
    for (int d = 0; d < 64; ++d) v += bq[4 * d + h] * Wk[(4 * d + h) * 256 + c];
    qb2[r] = v;
  } else if (t < 525568) {
    int o = t - 525312;
    float v = bm[o];
#pragma unroll 8
    for (int c2 = 0; c2 < 256; ++c2) v += Wm[o * 256 + c2] * bv[c2];
    btot[o] = v;
  }
}

// ---- qw_gemm: qW = W2T × query + qb2, written as [b][mt4][c][m'][h] bf16 tiles ---------
// grid = 1024 (vb: rt fastest so the 4 rt-blocks of one m-tile share an XCD/L2 line set)
__global__ __launch_bounds__(512)
void qw_gemm(const float* __restrict__ query, const unsigned short* __restrict__ W2T,
             const float* __restrict__ qb2, unsigned short* __restrict__ qWbuf) {
  __shared__ unsigned short Xl[32 * 256];
  const int tid = threadIdx.x;
  const int lane = tid & 63, wid = tid >> 6;
  const int wr = wid >> 1, wc = wid & 1;
  const int vb = (blockIdx.x & 7) * 128 + (blockIdx.x >> 3);
  const int rt = vb & 3;
  const int mt = (vb >> 2) & 127;
  const int b = vb >> 9;
  const int m0 = mt * 32;
  const float* Xb = query + (size_t)b * DM_ * M_ + m0;
  const int c4 = 4 * (tid & 7);
  const int ch0 = 4 * (tid >> 3);
  float4 f[4];
#pragma unroll
  for (int i = 0; i < 4; ++i) f[i] = *(const float4*)(Xb + (size_t)(ch0 + i) * M_ + c4);
#pragma unroll
  for (int j = 0; j < 4; ++j) {
    u16x4 u = { f2bf(((const float*)&f[0])[j]), f2bf(((const float*)&f[1])[j]),
                f2bf(((const float*)&f[2])[j]), f2bf(((const float*)&f[3])[j]) };
    *(u16x4*)((char*)Xl + swz512(c4 + j, 2 * ch0)) = u;
  }
  __syncthreads();
  f32x4 acc[4] = {};
  const int bcol = wc * 16 + (lane & 15);
  const int rdk = 16 * (lane >> 4);
  short8 a_cur[4], a_nxt[4];
#pragma unroll
  for (int fi = 0; fi < 4; ++fi)
    a_cur[fi] = *(const short8*)(W2T + (size_t)(((rt * 16 + wr * 4 + fi) * 64 + lane) * 8));
#pragma unroll
  for (int kgs = 0; kgs < 8; ++kgs) {
    if (kgs < 7) {
#pragma unroll
      for (int fi = 0; fi < 4; ++fi)
        a_nxt[fi] = *(const short8*)(W2T + (size_t)((((kgs + 1) * 64 + rt * 16 + wr * 4 + fi) * 64 + lane) * 8));
    }
    short8 bb = *(const short8*)((const char*)Xl + swz512(bcol, 64 * kgs + rdk));
#pragma unroll
    for (int fi = 0; fi < 4; ++fi)
      acc[fi] = __builtin_amdgcn_mfma_f32_16x16x32_bf16(a_cur[fi], bb, acc[fi], 0, 0, 0);
#pragma unroll
    for (int fi = 0; fi < 4; ++fi) a_cur[fi] = a_nxt[fi];
  }
  // epilogue: h = rt (uniform per block); tile elem = mt4*4096 + c*16 + m'*4 + h
  const int m = m0 + bcol;
  const int mt4 = m >> 2, mq = m & 3;
#pragma unroll
  for (int fi = 0; fi < 4; ++fi) {
#pragma unroll
    for (int r = 0; r < 4; ++r) {
      const int c = wr * 64 + fi * 16 + (lane >> 4) * 4 + r;
      const int rr = rt * 256 + c;
      qWbuf[((size_t)(b * 1024 + mt4)) * 4096 + c * 16 + mq * 4 + rt] =
          f2bf(acc[fi][r] + qb2[rr]);
    }
  }
}

// ---- attn_stream: scores + softmax + psum + pv ----------------------------------------
// grid = B*(M/4) = 2048 blocks, 512 threads (8 waves). Wave w: chans w*32..w*32+31.
// Lane (g=lane>>4, l15): m' = l15&3, kk0 = 4*(l15>>2); step i: chan = cb + 4i + g.
// ALL global loads are inline-asm with a hand-counted vmcnt queue:
//   issue order qW(1), K(8), V(8) -> 17 in flight; qW wait = vmcnt(16);
//   K[i] wait = vmcnt(15-i); V[j] wait = vmcnt(7-j). V loads stay outstanding
//   across three __syncthreads + softmax (asm loads are invisible to the
//   compiler's waitcnt pass, so barriers don't drain them).
__global__ __launch_bounds__(512, 3)
void attn_stream(const float* __restrict__ key, const float* __restrict__ value,
                 const unsigned short* __restrict__ qWbuf,
                 unsigned short* __restrict__ pvbuf, float* __restrict__ psum) {
  __shared__ unsigned short qwtile[4096];   // 8KB [c][m'][h] bf16; reused as pvstage [m][1024]
  __shared__ float scx[8][4][64];           // 8KB partial scores [wave][h][col]
  __shared__ float prob_lds[4][4][16];      // 1KB
  const int tid = threadIdx.x;
  const int lane = tid & 63, w = tid >> 6;
  const int vb = (blockIdx.x & 7) * 256 + (blockIdx.x >> 3);  // 2048 = 8 XCD-chunks x 256
  const int b = vb >> 10;
  const int m0 = (vb & 1023) * 4;
  const int g = lane >> 4, l15 = lane & 15;
  const int mq = l15 & 3;                    // lane's m (0..3)
  const int kq = 4 * (l15 >> 2);             // lane's kk base
  const int colw = mq * 16 + kq;             // col within the 64-col block
  const int cb = w * 32;
  const float* kb  = key   + (size_t)b * DM_ * MK_;
  const float* vbp = value + (size_t)b * DM_ * MK_;
  const unsigned short* qwsrc = qWbuf + ((size_t)(b * 1024 + (m0 >> 2))) * 4096;
  const uint32_t qwoff = (uint32_t)tid * 16u;
  const uint32_t kvo = ((uint32_t)(cb + g) * (uint32_t)MK_ +
                        (uint32_t)(m0 * KN_) + (uint32_t)colw) * 4u;
  uint4 qwv;
  f32x4 K[8], V[8];
  asm volatile("global_load_dwordx4 %0, %1, %2" : "=v"(qwv) : "v"(qwoff), "s"(qwsrc));
#define GK(i) asm volatile("global_load_dwordx4 %0, %1, %2" : "=v"(K[i]) : "v"(kvo + (i)*1048576u), "s"(kb))
#define GV(i) asm volatile("global_load_dwordx4 %0, %1, %2" : "=v"(V[i]) : "v"(kvo + (i)*1048576u), "s"(vbp))
  GK(0); GK(1); GK(2); GK(3); GK(4); GK(5); GK(6); GK(7);
  GV(0); GV(1); GV(2); GV(3); GV(4); GV(5); GV(6); GV(7);
#undef GK
#undef GV
  asm volatile("s_waitcnt vmcnt(16)" ::: "memory");   // qW ready; K+V still in flight
  __builtin_amdgcn_sched_barrier(0);
  *(uint4*)(qwtile + tid * 8) = qwv;                  // linear, conflict-free
  __syncthreads();
  // per-lane qW fragments: 8 x ds_read_b64, broadcast x4 lanes, bank-clean
  uint2 qvr[8];
#pragma unroll
  for (int i = 0; i < 8; ++i)
    qvr[i] = *(const uint2*)(qwtile + ((cb + 4 * i + g) * 16 + mq * 4));
  f32x4 s4[4] = {};
#define KSTEP(i, n) do { \
    asm volatile("s_waitcnt vmcnt(" #n ")" ::: "memory"); \
    __builtin_amdgcn_sched_barrier(0); \
    const uint32_t qx = qvr[i].x, qy = qvr[i].y; \
    s4[0] += K[i] * u2f(qx << 16); s4[1] += K[i] * u2f(qx & 0xFFFF0000u); \
    s4[2] += K[i] * u2f(qy << 16); s4[3] += K[i] * u2f(qy & 0xFFFF0000u); \
  } while (0)
  KSTEP(0, 15); KSTEP(1, 14); KSTEP(2, 13); KSTEP(3, 12);
  KSTEP(4, 11); KSTEP(5, 10); KSTEP(6, 9);  KSTEP(7, 8);
#undef KSTEP
  // reduce over the 4 chan-groups (lane bits 4,5)
#pragma unroll
  for (int h = 0; h < 4; ++h) {
#pragma unroll
    for (int j = 0; j < 4; ++j) {
      float v = s4[h][j];
      v += __shfl_xor(v, 16);
      v += __shfl_xor(v, 32);
      s4[h][j] = v;
    }
  }
  if (g == 0) {
#pragma unroll
    for (int h = 0; h < 4; ++h) *(f32x4*)&scx[w][h][colw] = s4[h];
  }
  __syncthreads();
  // ---- score finish + softmax (256 workers: h x 64 cols) ----
  if (tid < 256) {
    const int h2 = tid >> 6, col = tid & 63;
    float sc = 0.f;
#pragma unroll
    for (int w2 = 0; w2 < 8; ++w2) sc += scx[w2][h2][col];
    sc *= 0.125f;                          // 1/sqrt(64)
    float mx = sc;
#pragma unroll
    for (int d2 = 1; d2 < 16; d2 <<= 1) mx = fmaxf(mx, __shfl_xor(mx, d2));
    const float e = __expf(sc - mx);
    float sm = e;
#pragma unroll
    for (int d2 = 1; d2 < 16; d2 <<= 1) sm += __shfl_xor(sm, d2);
    prob_lds[h2][col >> 4][col & 15] = e / sm;
  }
  __syncthreads();
  if (tid < 64) {
    const int m = tid >> 4, kk = tid & 15;
    psum[((size_t)b * M_ + m0 + m) * KN_ + kk] =
        prob_lds[0][m][kk] + prob_lds[1][m][kk] + prob_lds[2][m][kk] + prob_lds[3][m][kk];
  }
  f32x4 pr[4];
#pragma unroll
  for (int h = 0; h < 4; ++h) pr[h] = *(const f32x4*)&prob_lds[h][mq][kq];
  // ---- PV: pv[m'][chan*4+h] = sum_kk prob[h][m'][kk]*value[chan][m',kk] ----
#define PSTEP(j, n) do { \
    asm volatile("s_waitcnt vmcnt(" #n ")" ::: "memory"); \
    __builtin_amdgcn_sched_barrier(0); \
    float p0 = pr[0][0]*V[j][0] + pr[0][1]*V[j][1] + pr[0][2]*V[j][2] + pr[0][3]*V[j][3]; \
    float p1 = pr[1][0]*V[j][0] + pr[1][1]*V[j][1] + pr[1][2]*V[j][2] + pr[1][3]*V[j][3]; \
    float p2 = pr[2][0]*V[j][0] + pr[2][1]*V[j][1] + pr[2][2]*V[j][2] + pr[2][3]*V[j][3]; \
    float p3 = pr[3][0]*V[j][0] + pr[3][1]*V[j][1] + pr[3][2]*V[j][2] + pr[3][3]*V[j][3]; \
    p0 += __shfl_xor(p0, 4); p0 += __shfl_xor(p0, 8); \
    p1 += __shfl_xor(p1, 4); p1 += __shfl_xor(p1, 8); \
    p2 += __shfl_xor(p2, 4); p2 += __shfl_xor(p2, 8); \
    p3 += __shfl_xor(p3, 4); p3 += __shfl_xor(p3, 8); \
    if (l15 < 4) { \
      uint2 o; \
      o.x = (uint32_t)f2bf(p0) | ((uint32_t)f2bf(p1) << 16); \
      o.y = (uint32_t)f2bf(p2) | ((uint32_t)f2bf(p3) << 16); \
      *(uint2*)(qwtile + (mq * 1024 + (cb + 4 * (j) + g) * 4)) = o; \
    } \
  } while (0)
  PSTEP(0, 7); PSTEP(1, 6); PSTEP(2, 5); PSTEP(3, 4);
  PSTEP(4, 3); PSTEP(5, 2); PSTEP(6, 1); PSTEP(7, 0);
#undef PSTEP
  __syncthreads();
  // ---- pv writeout: [b][m][kidx=(c*4+h)] bf16, 8KB contiguous per block ----
  {
    uint4 ov = *(const uint4*)(qwtile + tid * 8);
    *(uint4*)(pvbuf + (((size_t)b * M_ + m0 + (tid >> 7)) * 1024 + (tid & 127) * 8)) = ov;
  }
}

// ---- out_gemm: out[b][o][m] = Wmv × pv + btot ; grid = B*256 (16-col tiles), K=1024 ----
__global__ __launch_bounds__(512)
void out_gemm(const unsigned short* __restrict__ pvbuf, const unsigned short* __restrict__ Wmv,
              const float* __restrict__ btot, float* __restrict__ Out) {
  __shared__ unsigned short Xl[2][16 * 256];   // 8 KB per buffer, swizzled [col][k]
  const int tid = threadIdx.x;
  const int lane = tid & 63, wid = tid >> 6;   // 8 waves, wave = row-group
  const int b = blockIdx.x >> 8;
  const int m0 = (blockIdx.x & 255) * 16;
  const int scol = tid & 15, sq = tid >> 4;    // staging: col, k-8-group (sq 0..31)
  const int bcol = lane & 15;
  const int rdk = 16 * (lane >> 4);
  f32x4 acc[2] = {};
  for (int kp = 0; kp < 4; ++kp) {
    {
      const unsigned short* src = pvbuf + ((size_t)(b * M_ + m0 + scol) * 1024 + kp * 256 + sq * 8);
      uint4 v0 = *(const uint4*)src;
      *(uint4*)((char*)Xl[kp & 1] + swz512(scol, sq * 16)) = v0;
    }
    __syncthreads();
    short8 a_cur[2], a_nxt[2];
#pragma unroll
    for (int fi = 0; fi < 2; ++fi)
      a_cur[fi] = *(const short8*)(Wmv + (size_t)((((kp * 8) * 16 + wid * 2 + fi) * 64 + lane) * 8));
#pragma unroll
    for (int kgs = 0; kgs < 8; ++kgs) {
      if (kgs < 7) {
#pragma unroll
        for (int fi = 0; fi < 2; ++fi)
          a_nxt[fi] = *(const short8*)(Wmv + (size_t)((((kp * 8 + kgs + 1) * 16 + wid * 2 + fi) * 64 + lane) * 8));
      }
      short8 bb = *(const short8*)((const char*)Xl[kp & 1] + swz512(bcol, 64 * kgs + rdk));
#pragma unroll
      for (int fi = 0; fi < 2; ++fi)
        acc[fi] = __builtin_amdgcn_mfma_f32_16x16x32_bf16(a_cur[fi], bb, acc[fi], 0, 0, 0);
#pragma unroll
      for (int fi = 0; fi < 2; ++fi) a_cur[fi] = a_nxt[fi];
    }
    if (kp < 3) __syncthreads();
  }
#pragma unroll
  for (int fi = 0; fi < 2; ++fi) {
#pragma unroll
    for (int r = 0; r < 4; ++r) {
      const int o = (wid * 2 + fi) * 16 + (lane >> 4) * 4 + r;
      Out[(size_t)(b * DM_ + o) * M_ + m0 + bcol] = acc[fi][r] + btot[o];
    }
  }
}

extern "C" void kernel_launch(void* const* d_in, const int* in_sizes, int n_in,
                              void* d_out, int out_size, void* d_ws, size_t ws_size,
                              hipStream_t stream) {
  const float* query = (const float*)d_in[0];
  const float* key   = (const float*)d_in[1];
  const float* value = (const float*)d_in[2];
  const float* Wq = (const float*)d_in[3];
  const float* bq = (const float*)d_in[4];
  const float* Wk = (const float*)d_in[5];
  const float* bk = (const float*)d_in[6];  (void)bk;  // folded: softmax-invariant
  const float* Wv = (const float*)d_in[7];
  const float* bv = (const float*)d_in[8];
  const float* Wm = (const float*)d_in[9];
  const float* bm = (const float*)d_in[10];
  float* out  = (float*)d_out;
  float* psum = out + (size_t)B_ * DM_ * M_;   // outputs concatenated: out then prob_sum

  // ---- workspace layout ----
  const size_t Wmv_off  = 524288;                   // W2T: 512 KB bf16
  const size_t qb2_off  = 1048576;                  // Wmv: 512 KB bf16
  const size_t btot_off = 1052672;
  const size_t qW_off   = 1053696;                  // qW tiles: 16.78 MB bf16
  const size_t pv_off   = qW_off + (size_t)B_ * 1024 * M_ * 2;

  unsigned short* W2T   = (unsigned short*)d_ws;
  unsigned short* Wmv   = (unsigned short*)((char*)d_ws + Wmv_off);
  float* qb2            = (float*)((char*)d_ws + qb2_off);
  float* btot           = (float*)((char*)d_ws + btot_off);
  unsigned short* qWbuf = (unsigned short*)((char*)d_ws + qW_off);
  unsigned short* pvbuf = (unsigned short*)((char*)d_ws + pv_off);

  prep2<<<dim3(1027), dim3(512), 0, stream>>>(Wq, bq, Wk, Wv, bv, Wm, bm, W2T, Wmv, qb2, btot);
  qw_gemm<<<dim3(B_ * 4 * 128), dim3(512), 0, stream>>>(query, W2T, qb2, qWbuf);
  attn_stream<<<dim3(B_ * (M_ / 4)), dim3(512), 0, stream>>>(key, value, qWbuf, pvbuf, psum);
  out_gemm<<<dim3(B_ * 256), dim3(512), 0, stream>>>(pvbuf, Wmv, btot, out);
}